// Round 1
// baseline (153.782 us; speedup 1.0000x reference)
//
#include <hip/hip_runtime.h>
#include <cstddef>

#define P_TOT 50000
#define NPTSL 32
#define XL 432
#define YL 496
#define BSZ 4
#define OUTC 64
#define NMOM 35            // 7 feature sums + 28 upper-tri second moments
#define K1_BLK 256
#define NB1 ((P_TOT + K1_BLK - 1) / K1_BLK)   // 196

// ---------------------------------------------------------------------------
// K1: per-pillar feature moments (7 unique features; channels 7,8 dup 0,1).
// Deterministic: wave shuffle-reduce + fixed-order LDS combine -> per-block
// partial sums. Also scatters pillar id into the (b,y,x) map (gather path).
// ---------------------------------------------------------------------------
__global__ __launch_bounds__(256) void k1_moments(
    const float* __restrict__ pil, const int* __restrict__ coors,
    const int* __restrict__ npp, float* __restrict__ partials,
    int* __restrict__ map) {
  int p = blockIdx.x * K1_BLK + threadIdx.x;
  float a[NMOM];
#pragma unroll
  for (int i = 0; i < NMOM; i++) a[i] = 0.f;

  if (p < P_TOT) {
    const float4* q = (const float4*)(pil + (size_t)p * NPTSL * 4);
    // centroid: sum over ALL 32 (padded) points, divided by n (as reference)
    float sx = 0.f, sy = 0.f, sz = 0.f;
#pragma unroll
    for (int l = 0; l < NPTSL; l++) { float4 v = q[l]; sx += v.x; sy += v.y; sz += v.z; }
    int n = npp[p];
    float invn = 1.f / (float)n;
    float cx = sx * invn, cy = sy * invn, cz = sz * invn;
    int bi = coors[p * 4 + 0], xi = coors[p * 4 + 1], yi = coors[p * 4 + 2];
    if (map) map[((size_t)bi * YL + yi) * XL + xi] = p;
    float gx = (float)xi * 0.16f + 0.08f;
    float gy = (float)yi * 0.16f + -39.6f;
    for (int l = 0; l < n; l++) {          // only valid points contribute
      float4 v = q[l];
      float f[7];
      f[0] = v.x - gx; f[1] = v.y - gy; f[2] = v.z; f[3] = v.w;
      f[4] = v.x - cx; f[5] = v.y - cy; f[6] = v.z - cz;
      int k = 7;
#pragma unroll
      for (int i = 0; i < 7; i++) a[i] += f[i];
#pragma unroll
      for (int i = 0; i < 7; i++)
#pragma unroll
        for (int j = i; j < 7; j++) a[k++] += f[i] * f[j];
    }
  }

  __shared__ float red[4][NMOM];
  int lane = threadIdx.x & 63, wv = threadIdx.x >> 6;
#pragma unroll
  for (int i = 0; i < NMOM; i++) {
    float v = a[i];
#pragma unroll
    for (int off = 32; off > 0; off >>= 1) v += __shfl_down(v, off, 64);
    if (lane == 0) red[wv][i] = v;
  }
  __syncthreads();
  if (threadIdx.x < NMOM)
    partials[blockIdx.x * NMOM + threadIdx.x] =
        red[0][threadIdx.x] + red[1][threadIdx.x] +
        red[2][threadIdx.x] + red[3][threadIdx.x];
}

// ---------------------------------------------------------------------------
// K2: single block, 64 threads (= channels). Sum partials in fixed order,
// derive mean/var per channel via  mean=W·m,  E[x^2]=W^T S W, then
// scale = gamma*rsqrt(var+eps), shift = beta - mean*scale.
// ---------------------------------------------------------------------------
__global__ __launch_bounds__(64) void k2_stats(
    const float* __restrict__ partials, int nb,
    const float* __restrict__ w, const float* __restrict__ gamma,
    const float* __restrict__ beta, float* __restrict__ params) {
  __shared__ float tot[NMOM];
  int t = threadIdx.x;
  if (t < NMOM) {
    float s = 0.f;
    for (int b = 0; b < nb; b++) s += partials[b * NMOM + t];
    tot[t] = s;
  }
  __syncthreads();

  float wr[9];
#pragma unroll
  for (int i = 0; i < 9; i++) wr[i] = w[t * 9 + i];
  // effective 7-dim weights (channels 7,8 duplicate features 0,1)
  float we[7] = {wr[0] + wr[7], wr[1] + wr[8], wr[2], wr[3], wr[4], wr[5], wr[6]};

  const float invN = 1.f / (float)((size_t)P_TOT * NPTSL);
  float mean = 0.f;
#pragma unroll
  for (int i = 0; i < 7; i++) mean += we[i] * tot[i];
  mean *= invN;

  float ex2 = 0.f;
  int k = 7;
#pragma unroll
  for (int i = 0; i < 7; i++)
#pragma unroll
    for (int j = i; j < 7; j++) {
      float sij = tot[k++];
      ex2 += we[i] * we[j] * sij * ((i == j) ? 1.f : 2.f);
    }
  ex2 *= invN;

  float var = ex2 - mean * mean;
  float sc = gamma[t] * rsqrtf(var + 1e-3f);
  float sh = beta[t] - mean * sc;
  params[t] = sc;
  params[64 + t] = sh;
}

// ---------------------------------------------------------------------------
// K3: wave per pillar, lane = channel. Conv(9->64) + BN + ReLU + max over
// points. Masked points contribute relu(shift) when n<32 (x==0 exactly).
// DIRECT=0: write pooled[p][c] (coalesced 256B/wave).
// DIRECT=1: scatter straight into d_out (fallback path).
// ---------------------------------------------------------------------------
template <int DIRECT>
__global__ __launch_bounds__(256) void k3_pool(
    const float* __restrict__ pil, const int* __restrict__ coors,
    const int* __restrict__ npp, const float* __restrict__ w,
    const float* __restrict__ params, float* __restrict__ outp) {
  int wv = threadIdx.x >> 6, lane = threadIdx.x & 63;
  int p = blockIdx.x * 4 + wv;
  if (p >= P_TOT) return;

  float wr[9];
#pragma unroll
  for (int i = 0; i < 9; i++) wr[i] = w[lane * 9 + i];
  float we0 = wr[0] + wr[7], we1 = wr[1] + wr[8];
  float sc = params[lane], sh = params[64 + lane];

  const float4* q = (const float4*)(pil + (size_t)p * NPTSL * 4);
  // cooperative centroid: lanes 0..31 each hold one point, xor-tree reduce
  float4 mq = q[lane & 31];
  float sx = (lane < 32) ? mq.x : 0.f;
  float sy = (lane < 32) ? mq.y : 0.f;
  float sz = (lane < 32) ? mq.z : 0.f;
#pragma unroll
  for (int m = 1; m < 64; m <<= 1) {
    sx += __shfl_xor(sx, m, 64);
    sy += __shfl_xor(sy, m, 64);
    sz += __shfl_xor(sz, m, 64);
  }
  int n = npp[p];
  float invn = 1.f / (float)n;
  float cx = sx * invn, cy = sy * invn, cz = sz * invn;
  int bi = coors[p * 4 + 0], xi = coors[p * 4 + 1], yi = coors[p * 4 + 2];
  float gx = (float)xi * 0.16f + 0.08f;
  float gy = (float)yi * 0.16f + -39.6f;

  // running max; post-relu values are >=0, so init>=0 makes relu implicit.
  float pool = (n < NPTSL) ? fmaxf(sh, 0.f) : 0.f;
  for (int l = 0; l < n; l++) {           // uniform trip count per wave
    float4 v = q[l];
    float dot = we0 * (v.x - gx);
    dot = fmaf(we1, v.y - gy, dot);
    dot = fmaf(wr[2], v.z, dot);
    dot = fmaf(wr[3], v.w, dot);
    dot = fmaf(wr[4], v.x - cx, dot);
    dot = fmaf(wr[5], v.y - cy, dot);
    dot = fmaf(wr[6], v.z - cz, dot);
    float pv = fmaf(dot, sc, sh);
    pool = fmaxf(pool, pv);
  }

  if (DIRECT) {
    outp[(((size_t)bi * OUTC + lane) * YL + yi) * XL + xi] = pool;
  } else {
    outp[(size_t)p * OUTC + lane] = pool;
  }
}

// ---------------------------------------------------------------------------
// K4: dense output writer. lane = x (64-wide tile), loop channels.
// Stores fully coalesced (256B per instr). Pooled gathers: working set per
// wave = 64 ids x 256B = 16KB -> L1-resident, perfect reuse across channels.
// ---------------------------------------------------------------------------
__global__ __launch_bounds__(256) void k4_write(
    const int* __restrict__ map, const float* __restrict__ pooled,
    float* __restrict__ out) {
  int wv = threadIdx.x >> 6, lane = threadIdx.x & 63;
  int r = blockIdx.y * 4 + wv;            // 0..1983 = b*496+y
  int x = blockIdx.x * 64 + lane;         // 0..447
  int b = r / YL, y = r - b * YL;
  bool valid = (x < XL);
  int id = valid ? map[(size_t)r * XL + x] : -1;
  int idc = (id < 0) ? 0 : id;
  float msk = (id >= 0) ? 1.f : 0.f;
  const float4* pp = (const float4*)(pooled + (size_t)idc * OUTC);
  const size_t plane = (size_t)YL * XL;
  size_t obase = (((size_t)b * OUTC) * YL + y) * XL + x;
#pragma unroll
  for (int g = 0; g < 16; g++) {
    float4 v = pp[g];
    if (valid) {
      out[obase + (size_t)(4 * g + 0) * plane] = v.x * msk;
      out[obase + (size_t)(4 * g + 1) * plane] = v.y * msk;
      out[obase + (size_t)(4 * g + 2) * plane] = v.z * msk;
      out[obase + (size_t)(4 * g + 3) * plane] = v.w * msk;
    }
  }
}

// ---------------------------------------------------------------------------
extern "C" void kernel_launch(void* const* d_in, const int* in_sizes, int n_in,
                              void* d_out, int out_size, void* d_ws, size_t ws_size,
                              hipStream_t stream) {
  const float* pil   = (const float*)d_in[0];
  const int*   coors = (const int*)d_in[1];
  const int*   npp   = (const int*)d_in[2];
  const float* w     = (const float*)d_in[3];
  const float* gamma = (const float*)d_in[4];
  const float* beta  = (const float*)d_in[5];
  float* out = (float*)d_out;
  float* ws  = (float*)d_ws;

  float* partials = ws;                 // NB1*NMOM = 6860 floats
  float* params   = ws + 8192;          // 128 floats (scale[64], shift[64])
  float* pooled   = ws + 8704;          // P_TOT*64 floats
  int*   map      = (int*)(ws + 8704 + (size_t)P_TOT * OUTC);
  size_t need = ((size_t)8704 + (size_t)P_TOT * OUTC + (size_t)BSZ * YL * XL) * sizeof(float);

  if (ws_size >= need) {
    // gather path: id-map scatter (3.4MB) + dense coalesced output write
    hipMemsetAsync(map, 0xFF, (size_t)BSZ * YL * XL * sizeof(int), stream);
    hipLaunchKernelGGL(k1_moments, dim3(NB1), dim3(K1_BLK), 0, stream,
                       pil, coors, npp, partials, map);
    hipLaunchKernelGGL(k2_stats, dim3(1), dim3(64), 0, stream,
                       partials, NB1, w, gamma, beta, params);
    hipLaunchKernelGGL(k3_pool<0>, dim3(P_TOT / 4), dim3(256), 0, stream,
                       pil, coors, npp, w, params, pooled);
    hipLaunchKernelGGL(k4_write, dim3(7, (BSZ * YL) / 4), dim3(256), 0, stream,
                       map, pooled, out);
  } else {
    // fallback: zero canvas + direct scatter (needs only ~34KB ws)
    hipMemsetAsync(out, 0, (size_t)out_size * sizeof(float), stream);
    hipLaunchKernelGGL(k1_moments, dim3(NB1), dim3(K1_BLK), 0, stream,
                       pil, coors, npp, partials, (int*)nullptr);
    hipLaunchKernelGGL(k2_stats, dim3(1), dim3(64), 0, stream,
                       partials, NB1, w, gamma, beta, params);
    hipLaunchKernelGGL(k3_pool<1>, dim3(P_TOT / 4), dim3(256), 0, stream,
                       pil, coors, npp, w, params, out);
  }
}

// Round 2
// 153.438 us; speedup vs baseline: 1.0022x; 1.0022x over previous
//
#include <hip/hip_runtime.h>
#include <cstddef>

#define P_TOT 50000
#define NPTSL 32
#define XL 432
#define YL 496
#define BSZ 4
#define OUTC 64
#define NMOM 35            // 7 feature sums + 28 upper-tri second moments
#define K1_BLK 256
#define NB1 ((P_TOT + K1_BLK - 1) / K1_BLK)   // 196

// ---------------------------------------------------------------------------
// K0: fast fill (rocclr's fillBufferAligned ran at 27 GB/s for the 3.4MB map
// — 127us, 83% of the whole graph). Grid-stride int4 stores instead.
// ---------------------------------------------------------------------------
__global__ __launch_bounds__(256) void fill_i4(int4* __restrict__ dst,
                                               size_t n4, int val) {
  size_t i = (size_t)blockIdx.x * 256 + threadIdx.x;
  size_t stride = (size_t)gridDim.x * 256;
  int4 v = make_int4(val, val, val, val);
  for (; i < n4; i += stride) dst[i] = v;
}

// ---------------------------------------------------------------------------
// K1: per-pillar feature moments (7 unique features; channels 7,8 dup 0,1).
// Deterministic: wave shuffle-reduce + fixed-order LDS combine -> per-block
// partial sums. Also scatters pillar id into the (b,y,x) map (gather path).
// ---------------------------------------------------------------------------
__global__ __launch_bounds__(256) void k1_moments(
    const float* __restrict__ pil, const int* __restrict__ coors,
    const int* __restrict__ npp, float* __restrict__ partials,
    int* __restrict__ map) {
  int p = blockIdx.x * K1_BLK + threadIdx.x;
  float a[NMOM];
#pragma unroll
  for (int i = 0; i < NMOM; i++) a[i] = 0.f;

  if (p < P_TOT) {
    const float4* q = (const float4*)(pil + (size_t)p * NPTSL * 4);
    // centroid: sum over ALL 32 (padded) points, divided by n (as reference)
    float sx = 0.f, sy = 0.f, sz = 0.f;
#pragma unroll
    for (int l = 0; l < NPTSL; l++) { float4 v = q[l]; sx += v.x; sy += v.y; sz += v.z; }
    int n = npp[p];
    float invn = 1.f / (float)n;
    float cx = sx * invn, cy = sy * invn, cz = sz * invn;
    int bi = coors[p * 4 + 0], xi = coors[p * 4 + 1], yi = coors[p * 4 + 2];
    if (map) map[((size_t)bi * YL + yi) * XL + xi] = p;
    float gx = (float)xi * 0.16f + 0.08f;
    float gy = (float)yi * 0.16f + -39.6f;
    for (int l = 0; l < n; l++) {          // only valid points contribute
      float4 v = q[l];
      float f[7];
      f[0] = v.x - gx; f[1] = v.y - gy; f[2] = v.z; f[3] = v.w;
      f[4] = v.x - cx; f[5] = v.y - cy; f[6] = v.z - cz;
      int k = 7;
#pragma unroll
      for (int i = 0; i < 7; i++) a[i] += f[i];
#pragma unroll
      for (int i = 0; i < 7; i++)
#pragma unroll
        for (int j = i; j < 7; j++) a[k++] += f[i] * f[j];
    }
  }

  __shared__ float red[4][NMOM];
  int lane = threadIdx.x & 63, wv = threadIdx.x >> 6;
#pragma unroll
  for (int i = 0; i < NMOM; i++) {
    float v = a[i];
#pragma unroll
    for (int off = 32; off > 0; off >>= 1) v += __shfl_down(v, off, 64);
    if (lane == 0) red[wv][i] = v;
  }
  __syncthreads();
  if (threadIdx.x < NMOM)
    partials[blockIdx.x * NMOM + threadIdx.x] =
        red[0][threadIdx.x] + red[1][threadIdx.x] +
        red[2][threadIdx.x] + red[3][threadIdx.x];
}

// ---------------------------------------------------------------------------
// K2: single block, 64 threads (= channels). Sum partials in fixed order,
// derive mean/var per channel via  mean=W·m,  E[x^2]=W^T S W, then
// scale = gamma*rsqrt(var+eps), shift = beta - mean*scale.
// ---------------------------------------------------------------------------
__global__ __launch_bounds__(64) void k2_stats(
    const float* __restrict__ partials, int nb,
    const float* __restrict__ w, const float* __restrict__ gamma,
    const float* __restrict__ beta, float* __restrict__ params) {
  __shared__ float tot[NMOM];
  int t = threadIdx.x;
  if (t < NMOM) {
    float s = 0.f;
    for (int b = 0; b < nb; b++) s += partials[b * NMOM + t];
    tot[t] = s;
  }
  __syncthreads();

  float wr[9];
#pragma unroll
  for (int i = 0; i < 9; i++) wr[i] = w[t * 9 + i];
  // effective 7-dim weights (channels 7,8 duplicate features 0,1)
  float we[7] = {wr[0] + wr[7], wr[1] + wr[8], wr[2], wr[3], wr[4], wr[5], wr[6]};

  const float invN = 1.f / (float)((size_t)P_TOT * NPTSL);
  float mean = 0.f;
#pragma unroll
  for (int i = 0; i < 7; i++) mean += we[i] * tot[i];
  mean *= invN;

  float ex2 = 0.f;
  int k = 7;
#pragma unroll
  for (int i = 0; i < 7; i++)
#pragma unroll
    for (int j = i; j < 7; j++) {
      float sij = tot[k++];
      ex2 += we[i] * we[j] * sij * ((i == j) ? 1.f : 2.f);
    }
  ex2 *= invN;

  float var = ex2 - mean * mean;
  float sc = gamma[t] * rsqrtf(var + 1e-3f);
  float sh = beta[t] - mean * sc;
  params[t] = sc;
  params[64 + t] = sh;
}

// ---------------------------------------------------------------------------
// K3: wave per pillar, lane = channel. Conv(9->64) + BN + ReLU + max over
// points. Masked points contribute relu(shift) when n<32 (x==0 exactly).
// DIRECT=0: write pooled[p][c] (coalesced 256B/wave).
// DIRECT=1: scatter straight into d_out (fallback path).
// ---------------------------------------------------------------------------
template <int DIRECT>
__global__ __launch_bounds__(256) void k3_pool(
    const float* __restrict__ pil, const int* __restrict__ coors,
    const int* __restrict__ npp, const float* __restrict__ w,
    const float* __restrict__ params, float* __restrict__ outp) {
  int wv = threadIdx.x >> 6, lane = threadIdx.x & 63;
  int p = blockIdx.x * 4 + wv;
  if (p >= P_TOT) return;

  float wr[9];
#pragma unroll
  for (int i = 0; i < 9; i++) wr[i] = w[lane * 9 + i];
  float we0 = wr[0] + wr[7], we1 = wr[1] + wr[8];
  float sc = params[lane], sh = params[64 + lane];

  const float4* q = (const float4*)(pil + (size_t)p * NPTSL * 4);
  // cooperative centroid: lanes 0..31 each hold one point, xor-tree reduce
  float4 mq = q[lane & 31];
  float sx = (lane < 32) ? mq.x : 0.f;
  float sy = (lane < 32) ? mq.y : 0.f;
  float sz = (lane < 32) ? mq.z : 0.f;
#pragma unroll
  for (int m = 1; m < 64; m <<= 1) {
    sx += __shfl_xor(sx, m, 64);
    sy += __shfl_xor(sy, m, 64);
    sz += __shfl_xor(sz, m, 64);
  }
  int n = npp[p];
  float invn = 1.f / (float)n;
  float cx = sx * invn, cy = sy * invn, cz = sz * invn;
  int bi = coors[p * 4 + 0], xi = coors[p * 4 + 1], yi = coors[p * 4 + 2];
  float gx = (float)xi * 0.16f + 0.08f;
  float gy = (float)yi * 0.16f + -39.6f;

  // running max; post-relu values are >=0, so init>=0 makes relu implicit.
  float pool = (n < NPTSL) ? fmaxf(sh, 0.f) : 0.f;
  for (int l = 0; l < n; l++) {           // uniform trip count per wave
    float4 v = q[l];
    float dot = we0 * (v.x - gx);
    dot = fmaf(we1, v.y - gy, dot);
    dot = fmaf(wr[2], v.z, dot);
    dot = fmaf(wr[3], v.w, dot);
    dot = fmaf(wr[4], v.x - cx, dot);
    dot = fmaf(wr[5], v.y - cy, dot);
    dot = fmaf(wr[6], v.z - cz, dot);
    float pv = fmaf(dot, sc, sh);
    pool = fmaxf(pool, pv);
  }

  if (DIRECT) {
    outp[(((size_t)bi * OUTC + lane) * YL + yi) * XL + xi] = pool;
  } else {
    outp[(size_t)p * OUTC + lane] = pool;
  }
}

// ---------------------------------------------------------------------------
// K4: dense output writer. lane = x (64-wide tile), loop channels.
// Stores fully coalesced (256B per instr). Pooled gathers: working set per
// wave = 64 ids x 256B = 16KB -> L1-resident, perfect reuse across channels.
// ---------------------------------------------------------------------------
__global__ __launch_bounds__(256) void k4_write(
    const int* __restrict__ map, const float* __restrict__ pooled,
    float* __restrict__ out) {
  int wv = threadIdx.x >> 6, lane = threadIdx.x & 63;
  int r = blockIdx.y * 4 + wv;            // 0..1983 = b*496+y
  int x = blockIdx.x * 64 + lane;         // 0..447
  int b = r / YL, y = r - b * YL;
  bool valid = (x < XL);
  int id = valid ? map[(size_t)r * XL + x] : -1;
  int idc = (id < 0) ? 0 : id;
  float msk = (id >= 0) ? 1.f : 0.f;
  const float4* pp = (const float4*)(pooled + (size_t)idc * OUTC);
  const size_t plane = (size_t)YL * XL;
  size_t obase = (((size_t)b * OUTC) * YL + y) * XL + x;
#pragma unroll
  for (int g = 0; g < 16; g++) {
    float4 v = pp[g];
    if (valid) {
      out[obase + (size_t)(4 * g + 0) * plane] = v.x * msk;
      out[obase + (size_t)(4 * g + 1) * plane] = v.y * msk;
      out[obase + (size_t)(4 * g + 2) * plane] = v.z * msk;
      out[obase + (size_t)(4 * g + 3) * plane] = v.w * msk;
    }
  }
}

// ---------------------------------------------------------------------------
extern "C" void kernel_launch(void* const* d_in, const int* in_sizes, int n_in,
                              void* d_out, int out_size, void* d_ws, size_t ws_size,
                              hipStream_t stream) {
  const float* pil   = (const float*)d_in[0];
  const int*   coors = (const int*)d_in[1];
  const int*   npp   = (const int*)d_in[2];
  const float* w     = (const float*)d_in[3];
  const float* gamma = (const float*)d_in[4];
  const float* beta  = (const float*)d_in[5];
  float* out = (float*)d_out;
  float* ws  = (float*)d_ws;

  float* partials = ws;                 // NB1*NMOM = 6860 floats
  float* params   = ws + 8192;          // 128 floats (scale[64], shift[64])
  float* pooled   = ws + 8704;          // P_TOT*64 floats
  int*   map      = (int*)(ws + 8704 + (size_t)P_TOT * OUTC);
  size_t need = ((size_t)8704 + (size_t)P_TOT * OUTC + (size_t)BSZ * YL * XL) * sizeof(float);

  if (ws_size >= need) {
    // gather path: id-map fill (3.4MB, custom kernel) + dense coalesced write
    const size_t map_n4 = (size_t)BSZ * YL * XL / 4;          // 214272
    hipLaunchKernelGGL(fill_i4, dim3(837), dim3(256), 0, stream,
                       (int4*)map, map_n4, -1);
    hipLaunchKernelGGL(k1_moments, dim3(NB1), dim3(K1_BLK), 0, stream,
                       pil, coors, npp, partials, map);
    hipLaunchKernelGGL(k2_stats, dim3(1), dim3(64), 0, stream,
                       partials, NB1, w, gamma, beta, params);
    hipLaunchKernelGGL(k3_pool<0>, dim3(P_TOT / 4), dim3(256), 0, stream,
                       pil, coors, npp, w, params, pooled);
    hipLaunchKernelGGL(k4_write, dim3(7, (BSZ * YL) / 4), dim3(256), 0, stream,
                       map, pooled, out);
  } else {
    // fallback: zero canvas (custom fill) + direct scatter (~34KB ws)
    const size_t out_n4 = (size_t)out_size / 4;
    hipLaunchKernelGGL(fill_i4, dim3(2048), dim3(256), 0, stream,
                       (int4*)out, out_n4, 0);
    hipLaunchKernelGGL(k1_moments, dim3(NB1), dim3(K1_BLK), 0, stream,
                       pil, coors, npp, partials, (int*)nullptr);
    hipLaunchKernelGGL(k2_stats, dim3(1), dim3(64), 0, stream,
                       partials, NB1, w, gamma, beta, params);
    hipLaunchKernelGGL(k3_pool<1>, dim3(P_TOT / 4), dim3(256), 0, stream,
                       pil, coors, npp, w, params, out);
  }
}